// Round 1
// baseline (560.061 us; speedup 1.0000x reference)
//
#include <hip/hip_runtime.h>

#define NPTS 100000
#define NK   1600000   // NPTS * 16

// ---------------------------------------------------------------------------
// Kernel A: y = x @ W3 + b3   (N x 64) -- one thread per output element
// ---------------------------------------------------------------------------
__global__ __launch_bounds__(256) void k_xw3(
    const float* __restrict__ x, const float* __restrict__ W3,
    const float* __restrict__ b3, float* __restrict__ y)
{
  int t = blockIdx.x * 256 + threadIdx.x;
  int i = __builtin_amdgcn_readfirstlane(t >> 6);   // wave-uniform row
  int c = t & 63;
  if (i >= NPTS) return;
  const float* xr = x + i * 64;
  float acc = b3[c];
#pragma unroll
  for (int k = 0; k < 64; ++k)
    acc = fmaf(xr[k], W3[k * 64 + c], acc);
  y[i * 64 + c] = acc;
}

// ---------------------------------------------------------------------------
// Kernel B: main fused per-(n,j) pipeline. 16 consecutive lanes = one point.
// ---------------------------------------------------------------------------
__global__ __launch_bounds__(256) void k_main(
    const float* __restrict__ p, const float* __restrict__ x,
    const int* __restrict__ knn,
    const float* __restrict__ W01, const float* __restrict__ b01,
    const float* __restrict__ Wbil, const float* __restrict__ bbil,
    const float* __restrict__ Wp1, const float* __restrict__ bp1,
    const float* __restrict__ bnp_s, const float* __restrict__ bnp_b,
    const float* __restrict__ Wp2, const float* __restrict__ bp2,
    const float* __restrict__ W2a, const float* __restrict__ bn2a_s, const float* __restrict__ bn2a_b,
    const float* __restrict__ W2b, const float* __restrict__ bn2b_s, const float* __restrict__ bn2b_b,
    const float* __restrict__ W2c, const float* __restrict__ b2c,
    const float* __restrict__ y,
    float* __restrict__ x_out, float* __restrict__ x_knn)
{
  __shared__ float e2s[16][256];   // bilinear outputs, runtime-o staging
  const int tid = threadIdx.x;
  const int row = blockIdx.x * 256 + tid;
  if (row >= NK) return;
  const int n = row >> 4;
  const int j = row & 15;
  const int idx = knn[row];

  const float pr0 = p[idx * 3 + 0] - p[n * 3 + 0];
  const float pr1 = p[idx * 3 + 1] - p[n * 3 + 1];
  const float pr2 = p[idx * 3 + 2] - p[n * 3 + 2];

  // ---- e = relu([pr, x[idx]] @ W01 + b01)  (67x16)
  float e[16];
#pragma unroll
  for (int o = 0; o < 16; ++o)
    e[o] = b01[o] + pr0 * W01[0 * 16 + o] + pr1 * W01[1 * 16 + o] + pr2 * W01[2 * 16 + o];
  const float4* x4 = (const float4*)x;
#pragma unroll 2
  for (int k0 = 0; k0 < 16; ++k0) {
    float4 xv = x4[idx * 16 + k0];
#pragma unroll
    for (int o = 0; o < 16; ++o) {
      e[o] = fmaf(xv.x, W01[(3 + k0 * 4 + 0) * 16 + o], e[o]);
      e[o] = fmaf(xv.y, W01[(3 + k0 * 4 + 1) * 16 + o], e[o]);
      e[o] = fmaf(xv.z, W01[(3 + k0 * 4 + 2) * 16 + o], e[o]);
      e[o] = fmaf(xv.w, W01[(3 + k0 * 4 + 3) * 16 + o], e[o]);
    }
  }
#pragma unroll
  for (int o = 0; o < 16; ++o) e[o] = fmaxf(e[o], 0.f);

  // ---- bilinear: e2[o] = e^T Wbil[o] e + bbil[o]
#pragma unroll 1
  for (int o = 0; o < 16; ++o) {
    const float* M = Wbil + o * 256;
    float t[16];
#pragma unroll
    for (int jj = 0; jj < 16; ++jj) t[jj] = 0.f;
#pragma unroll
    for (int i = 0; i < 16; ++i) {
#pragma unroll
      for (int jj = 0; jj < 16; ++jj)
        t[jj] = fmaf(e[i], M[i * 16 + jj], t[jj]);
    }
    float acc = bbil[o];
#pragma unroll
    for (int jj = 0; jj < 16; ++jj) acc = fmaf(t[jj], e[jj], acc);
    e2s[o][tid] = acc;   // same-thread RAW only; no barrier needed
  }

  // ---- linear_p front (3->3, BN, relu) -> q;  shrink[b] = sum_a pe[a*16+b]
  float q[3];
#pragma unroll
  for (int i = 0; i < 3; ++i) {
    float v = bp1[i] + pr0 * Wp1[0 * 3 + i] + pr1 * Wp1[1 * 3 + i] + pr2 * Wp1[2 * 3 + i];
    q[i] = fmaxf(fmaf(v, bnp_s[i], bnp_b[i]), 0.f);
  }
  float sh[16];
#pragma unroll
  for (int b = 0; b < 16; ++b) sh[b] = 0.f;
#pragma unroll 1
  for (int a = 0; a < 4; ++a) {
#pragma unroll
    for (int b = 0; b < 16; ++b) {
      int c = a * 16 + b;
      float pe = bp2[c] + q[0] * Wp2[0 * 64 + c] + q[1] * Wp2[1 * 64 + c] + q[2] * Wp2[2 * 64 + c];
      sh[b] += pe;
    }
  }

  // ---- channelMixMLPs02: ef=[e2,sh] -> 64 -> 8 -> 8
  float e2r[16];
#pragma unroll
  for (int i = 0; i < 16; ++i) e2r[i] = e2s[i][tid];
  float h2[8];
#pragma unroll
  for (int m = 0; m < 8; ++m) h2[m] = 0.f;
#pragma unroll 4
  for (int c = 0; c < 64; ++c) {
    float a = e2r[0] * W2a[c];
#pragma unroll
    for (int i = 1; i < 16; ++i) a = fmaf(e2r[i], W2a[i * 64 + c], a);
#pragma unroll
    for (int i = 0; i < 16; ++i) a = fmaf(sh[i], W2a[(16 + i) * 64 + c], a);
    a = fmaxf(fmaf(a, bn2a_s[c], bn2a_b[c]), 0.f);
#pragma unroll
    for (int m = 0; m < 8; ++m) h2[m] = fmaf(a, W2b[c * 8 + m], h2[m]);
  }
  float h3[8];
#pragma unroll
  for (int b = 0; b < 8; ++b) h3[b] = b2c[b];
#pragma unroll
  for (int m = 0; m < 8; ++m) {
    float r = fmaxf(fmaf(h2[m], bn2b_s[m], bn2b_b[m]), 0.f);
#pragma unroll
    for (int b = 0; b < 8; ++b) h3[b] = fmaf(r, W2c[m * 8 + b], h3[b]);
  }

  // ---- softmax over the 16 neighbors (16-lane groups)
  float wv[8];
#pragma unroll
  for (int b = 0; b < 8; ++b) {
    float mx = h3[b];
    mx = fmaxf(mx, __shfl_xor(mx, 1, 16));
    mx = fmaxf(mx, __shfl_xor(mx, 2, 16));
    mx = fmaxf(mx, __shfl_xor(mx, 4, 16));
    mx = fmaxf(mx, __shfl_xor(mx, 8, 16));
    float ex = __expf(h3[b] - mx);
    float s = ex;
    s += __shfl_xor(s, 1, 16);
    s += __shfl_xor(s, 2, 16);
    s += __shfl_xor(s, 4, 16);
    s += __shfl_xor(s, 8, 16);
    wv[b] = ex / s;
  }

  // ---- phase 2: x_knn = (y[idx] + pe) * w ; x_out = sum_k x_knn
  const float4* y4 = (const float4*)y;
  float4* xk4 = (float4*)(x_knn + row * 64);
  float xo[4] = {0.f, 0.f, 0.f, 0.f};
#pragma unroll
  for (int c0 = 0; c0 < 16; ++c0) {
    float4 yv = y4[idx * 16 + c0];
    float comp[4] = {yv.x, yv.y, yv.z, yv.w};
    float vals[4];
#pragma unroll
    for (int cc = 0; cc < 4; ++cc) {
      const int c = c0 * 4 + cc;
      float pe = bp2[c] + q[0] * Wp2[c] + q[1] * Wp2[64 + c] + q[2] * Wp2[128 + c];
      float val = (comp[cc] + pe) * wv[c & 7];
      vals[cc] = val;
      float r = val;
      r += __shfl_xor(r, 1, 16);
      r += __shfl_xor(r, 2, 16);
      r += __shfl_xor(r, 4, 16);
      r += __shfl_xor(r, 8, 16);
      if (j == (c & 15)) xo[c >> 4] = r;   // c>>4, c&15 are compile-time consts
    }
    float4 st; st.x = vals[0]; st.y = vals[1]; st.z = vals[2]; st.w = vals[3];
    xk4[c0] = st;
  }
#pragma unroll
  for (int g = 0; g < 4; ++g)
    x_out[n * 64 + g * 16 + j] = xo[g];
}

// ---------------------------------------------------------------------------
// Kernel C: finalize tail outputs (knn_idx as float, p_r) -- overwrites the
// region kernel A used for y (stream-ordered, so safe).
// ---------------------------------------------------------------------------
__global__ __launch_bounds__(256) void k_tail(
    const float* __restrict__ p, const int* __restrict__ knn,
    float* __restrict__ knn_f, float* __restrict__ p_r)
{
  int row = blockIdx.x * 256 + threadIdx.x;
  if (row >= NK) return;
  int n = row >> 4;
  int idx = knn[row];
  knn_f[row] = (float)idx;
  p_r[row * 3 + 0] = p[idx * 3 + 0] - p[n * 3 + 0];
  p_r[row * 3 + 1] = p[idx * 3 + 1] - p[n * 3 + 1];
  p_r[row * 3 + 2] = p[idx * 3 + 2] - p[n * 3 + 2];
}

// ---------------------------------------------------------------------------
extern "C" void kernel_launch(void* const* d_in, const int* in_sizes, int n_in,
                              void* d_out, int out_size, void* d_ws, size_t ws_size,
                              hipStream_t stream)
{
  const float* p    = (const float*)d_in[0];
  const float* x    = (const float*)d_in[1];
  const int*   knn  = (const int*)d_in[2];
  const float* W01  = (const float*)d_in[3];
  const float* b01  = (const float*)d_in[4];
  const float* Wbil = (const float*)d_in[5];
  const float* bbil = (const float*)d_in[6];
  const float* Wp1  = (const float*)d_in[7];
  const float* bp1  = (const float*)d_in[8];
  const float* bnps = (const float*)d_in[9];
  const float* bnpb = (const float*)d_in[10];
  const float* Wp2  = (const float*)d_in[11];
  const float* bp2  = (const float*)d_in[12];
  const float* W2a  = (const float*)d_in[13];
  const float* s2a  = (const float*)d_in[14];
  const float* b2a  = (const float*)d_in[15];
  const float* W2b  = (const float*)d_in[16];
  const float* s2b  = (const float*)d_in[17];
  const float* b2b  = (const float*)d_in[18];
  const float* W2c  = (const float*)d_in[19];
  const float* b2c  = (const float*)d_in[20];
  const float* W3   = (const float*)d_in[21];
  const float* b3   = (const float*)d_in[22];

  float* outF  = (float*)d_out;
  float* x_out = outF;                 // [N,64]        6,400,000 floats
  float* x_knn = outF + 6400000;       // [N,16,64]   102,400,000 floats
  float* knn_f = outF + 108800000;     // [N,16]        1,600,000 floats
  float* p_r   = outF + 110400000;     // [N,16,3]      4,800,000 floats
  float* y     = knn_f;                // reuse tail (6.4M floats) for x@W3+b3

  k_xw3<<<25000, 256, 0, stream>>>(x, W3, b3, y);
  k_main<<<6250, 256, 0, stream>>>(p, x, knn, W01, b01, Wbil, bbil, Wp1, bp1,
                                   bnps, bnpb, Wp2, bp2, W2a, s2a, b2a,
                                   W2b, s2b, b2b, W2c, b2c, y, x_out, x_knn);
  k_tail<<<6250, 256, 0, stream>>>(p, knn, knn_f, p_r);
}